// Round 1
// baseline (184.520 us; speedup 1.0000x reference)
//
#include <hip/hip_runtime.h>
#include <math.h>

#define NT  16384
#define HID 2048
#define NE  8

constexpr int TOP_OFF  = 0;                 // top_scores  (NT,2)
constexpr int SC_OFF   = NT * 2;            // scores      (NT,8)   = 32768
constexpr int IDX_OFF  = SC_OFF + NT * NE;  // indices     (NT,2)   = 163840
constexpr int HIST_OFF = IDX_OFF + NT * 2;  // counts      (8)      = 196608
constexpr int ENT_OFF  = HIST_OFF + NE;     // entropy     (1)      = 196616

__global__ void init_tail(float* __restrict__ out) {
  const int i = threadIdx.x;
  if (i < NE + 1) out[HIST_OFF + i] = 0.0f;
}

__global__ __launch_bounds__(256, 2)
void router_kernel(const float* __restrict__ x, const float* __restrict__ W,
                   const float* __restrict__ bias, float* __restrict__ out) {
  __shared__ float sW[NE * HID];   // 64 KiB
  __shared__ int   sHist[NE];
  __shared__ float sEnt;

  const int tid  = threadIdx.x;
  const int wave = tid >> 6;
  const int lane = tid & 63;

  // Stage W into LDS: 16384 floats = 4096 float4, 16 per thread (coalesced).
  {
    const float4* Wv  = reinterpret_cast<const float4*>(W);
    float4*       sWv = reinterpret_cast<float4*>(sW);
#pragma unroll
    for (int i = 0; i < 16; ++i) sWv[i * 256 + tid] = Wv[i * 256 + tid];
  }
  if (tid < NE) sHist[tid] = 0;
  if (tid == 0) sEnt = 0.0f;

  // Expert bias (uniform -> scalar loads), static indexing only.
  float bs[NE];
#pragma unroll
  for (int e = 0; e < NE; ++e) bs[e] = bias[e];

  __syncthreads();

  const int tokBase = blockIdx.x * 32 + wave * 8;

  for (int g = 0; g < 2; ++g) {
    const int t0 = tokBase + g * 4;
    float acc[4][NE];
#pragma unroll
    for (int t = 0; t < 4; ++t)
#pragma unroll
      for (int e = 0; e < NE; ++e) acc[t][e] = 0.0f;

    const float* xb = x + (size_t)t0 * HID;

#pragma unroll
    for (int it = 0; it < 8; ++it) {
      const int off = it * 256 + lane * 4;  // element offset within a row
      float4 xv[4];
#pragma unroll
      for (int t = 0; t < 4; ++t)
        xv[t] = *reinterpret_cast<const float4*>(xb + (size_t)t * HID + off);
#pragma unroll
      for (int e = 0; e < NE; ++e) {
        const float4 wv = *reinterpret_cast<const float4*>(sW + e * HID + off);
#pragma unroll
        for (int t = 0; t < 4; ++t) {
          acc[t][e] += xv[t].x * wv.x;
          acc[t][e] += xv[t].y * wv.y;
          acc[t][e] += xv[t].z * wv.z;
          acc[t][e] += xv[t].w * wv.w;
        }
      }
    }

    // Butterfly reduce across 64 lanes; every lane ends with all 32 full sums.
#pragma unroll
    for (int t = 0; t < 4; ++t)
#pragma unroll
      for (int e = 0; e < NE; ++e) {
        float v = acc[t][e];
        v += __shfl_xor(v, 32, 64);
        v += __shfl_xor(v, 16, 64);
        v += __shfl_xor(v,  8, 64);
        v += __shfl_xor(v,  4, 64);
        v += __shfl_xor(v,  2, 64);
        v += __shfl_xor(v,  1, 64);
        acc[t][e] = v;
      }

    // Lane l (<4) handles token t0+l. Select its logits WITHOUT runtime array
    // indexing (rule: runtime-indexed reg arrays spill to scratch) — cndmask.
    float le[NE];
#pragma unroll
    for (int e = 0; e < NE; ++e) {
      float v = acc[0][e];
      v = (lane == 1) ? acc[1][e] : v;
      v = (lane == 2) ? acc[2][e] : v;
      v = (lane == 3) ? acc[3][e] : v;
      le[e] = v;
    }

    if (lane < 4) {
      const int tok = t0 + lane;
      float sc[NE];
#pragma unroll
      for (int e = 0; e < NE; ++e) sc[e] = 1.0f / (1.0f + __expf(-le[e]));

      // top-2 on biased scores; strict > keeps lowest index on ties (jax top_k)
      float m1 = -1e30f, m2 = -1e30f, s1 = 0.0f, s2 = 0.0f;
      int i1 = 0, i2 = 0;
#pragma unroll
      for (int e = 0; e < NE; ++e) {
        const float be = sc[e] + bs[e];
        const bool g1 = be > m1;
        const bool g2 = be > m2;
        i2 = g1 ? i1 : (g2 ? e  : i2);
        m2 = g1 ? m1 : (g2 ? be : m2);
        s2 = g1 ? s1 : (g2 ? sc[e] : s2);
        i1 = g1 ? e  : i1;
        m1 = g1 ? be : m1;
        s1 = g1 ? sc[e] : s1;
      }

      const float denom = s1 + s2 + 1e-20f;
      const float n1 = s1 / denom;
      const float n2 = s2 / denom;

      *reinterpret_cast<float2*>(out + TOP_OFF + (size_t)tok * 2) =
          make_float2(n1, n2);
      *reinterpret_cast<float2*>(out + IDX_OFF + (size_t)tok * 2) =
          make_float2((float)i1, (float)i2);
      *reinterpret_cast<float4*>(out + SC_OFF + (size_t)tok * 8) =
          make_float4(sc[0], sc[1], sc[2], sc[3]);
      *reinterpret_cast<float4*>(out + SC_OFF + (size_t)tok * 8 + 4) =
          make_float4(sc[4], sc[5], sc[6], sc[7]);

      const float ent = -(n1 * __logf(n1) + n2 * __logf(n2));
      atomicAdd(&sEnt, ent);
      atomicAdd(&sHist[i1], 1);
      atomicAdd(&sHist[i2], 1);
    }
  }

  __syncthreads();
  if (tid < NE) atomicAdd(out + HIST_OFF + tid, (float)sHist[tid]);
  if (tid == 0) atomicAdd(out + ENT_OFF, sEnt * (1.0f / (float)NT));
}

extern "C" void kernel_launch(void* const* d_in, const int* in_sizes, int n_in,
                              void* d_out, int out_size, void* d_ws, size_t ws_size,
                              hipStream_t stream) {
  (void)in_sizes; (void)n_in; (void)out_size; (void)d_ws; (void)ws_size;
  const float* x    = (const float*)d_in[0];
  const float* W    = (const float*)d_in[1];
  const float* bias = (const float*)d_in[2];
  float* out = (float*)d_out;

  // d_out is poisoned before timing: zero the atomic-accumulated tail first.
  init_tail<<<1, 64, 0, stream>>>(out);
  // 512 blocks x 256 threads; 32 tokens/block; 2 blocks/CU (LDS-limited).
  router_kernel<<<512, 256, 0, stream>>>(x, W, bias, out);
}

// Round 2
// 56.307 us; speedup vs baseline: 3.2770x; 3.2770x over previous
//
#include <hip/hip_runtime.h>
#include <math.h>

#define NT  16384
#define HID 2048
#define NE  8

constexpr int TOP_OFF  = 0;                 // top_scores  (NT,2)
constexpr int SC_OFF   = NT * 2;            // scores      (NT,8)
constexpr int IDX_OFF  = SC_OFF + NT * NE;  // indices     (NT,2)
constexpr int HIST_OFF = IDX_OFF + NT * 2;  // counts      (8)
constexpr int ENT_OFF  = HIST_OFF + NE;     // entropy     (1)

__global__ void init_tail(float* __restrict__ out) {
  const int i = threadIdx.x;
  if (i < NE + 1) out[HIST_OFF + i] = 0.0f;
}

// X-macro over experts: everything below uses NAMED scalars only — no
// indexable per-thread arrays anywhere (previous version spilled ~210 MB
// of scratch to HBM; named scalars cannot be demoted to scratch).
#define FOR_E(F) F(0) F(1) F(2) F(3) F(4) F(5) F(6) F(7)

__global__ __launch_bounds__(256, 2)
void router_kernel(const float* __restrict__ x, const float* __restrict__ W,
                   const float* __restrict__ bias, float* __restrict__ out) {
  __shared__ float sW[NE * HID];   // 64 KiB
  __shared__ int   sHist[NE];
  __shared__ float sEnt;

  const int tid  = threadIdx.x;
  const int wave = tid >> 6;
  const int lane = tid & 63;

  // Stage W into LDS: 16384 floats = 4096 float4, 16 per thread (coalesced).
  {
    const float4* Wv  = reinterpret_cast<const float4*>(W);
    float4*       sWv = reinterpret_cast<float4*>(sW);
#pragma unroll
    for (int i = 0; i < 16; ++i) sWv[i * 256 + tid] = Wv[i * 256 + tid];
  }
  if (tid < NE) sHist[tid] = 0;
  if (tid == 0) sEnt = 0.0f;

#define DECL_BS(e) const float bs_##e = bias[e];
  FOR_E(DECL_BS)

  __syncthreads();

  // 4 tokens per wave, 16 per block, 1024 blocks. No outer token loop.
  const int t0 = blockIdx.x * 16 + wave * 4;
  const float* xb = x + (size_t)t0 * HID;

#define DECL_ACC(e) float a0_##e = 0.f, a1_##e = 0.f, a2_##e = 0.f, a3_##e = 0.f;
  FOR_E(DECL_ACC)

#pragma unroll
  for (int it = 0; it < 8; ++it) {
    const int off = it * 256 + lane * 4;  // element offset within a row
    const float4 x0 = *reinterpret_cast<const float4*>(xb + off);
    const float4 x1 = *reinterpret_cast<const float4*>(xb + HID + off);
    const float4 x2 = *reinterpret_cast<const float4*>(xb + 2 * HID + off);
    const float4 x3 = *reinterpret_cast<const float4*>(xb + 3 * HID + off);
#define STEP_E(e)                                                          \
    {                                                                      \
      const float4 wv = *reinterpret_cast<const float4*>(sW + e * HID + off); \
      a0_##e += x0.x * wv.x + x0.y * wv.y + x0.z * wv.z + x0.w * wv.w;     \
      a1_##e += x1.x * wv.x + x1.y * wv.y + x1.z * wv.z + x1.w * wv.w;     \
      a2_##e += x2.x * wv.x + x2.y * wv.y + x2.z * wv.z + x2.w * wv.w;     \
      a3_##e += x3.x * wv.x + x3.y * wv.y + x3.z * wv.z + x3.w * wv.w;     \
    }
    FOR_E(STEP_E)
  }

  // Butterfly reduce each named accumulator across all 64 lanes.
#define RED(v)                                                             \
  { v += __shfl_xor(v, 32, 64); v += __shfl_xor(v, 16, 64);                \
    v += __shfl_xor(v,  8, 64); v += __shfl_xor(v,  4, 64);                \
    v += __shfl_xor(v,  2, 64); v += __shfl_xor(v,  1, 64); }
#define RED_E(e) RED(a0_##e) RED(a1_##e) RED(a2_##e) RED(a3_##e)
  FOR_E(RED_E)

  // Lane l (<4) takes token t0+l's logits via cndmask chains (no arrays).
#define SEL_E(e)                                                           \
  float le_##e = a0_##e;                                                   \
  le_##e = (lane == 1) ? a1_##e : le_##e;                                  \
  le_##e = (lane == 2) ? a2_##e : le_##e;                                  \
  le_##e = (lane == 3) ? a3_##e : le_##e;
  FOR_E(SEL_E)

  if (lane < 4) {
    const int tok = t0 + lane;
#define SIG_E(e) const float sc_##e = 1.0f / (1.0f + __expf(-le_##e));
    FOR_E(SIG_E)

    // top-2 on biased scores; strict > keeps lowest index on ties (jax top_k)
    float m1 = -1e30f, m2 = -1e30f, s1 = 0.0f, s2 = 0.0f;
    int i1 = 0, i2 = 0;
#define TOP_E(e)                                                           \
    {                                                                      \
      const float be = sc_##e + bs_##e;                                    \
      const bool g1 = be > m1;                                             \
      const bool g2 = be > m2;                                             \
      i2 = g1 ? i1 : (g2 ? e     : i2);                                    \
      m2 = g1 ? m1 : (g2 ? be    : m2);                                    \
      s2 = g1 ? s1 : (g2 ? sc_##e : s2);                                   \
      i1 = g1 ? e     : i1;                                                \
      m1 = g1 ? be    : m1;                                                \
      s1 = g1 ? sc_##e : s1;                                               \
    }
    FOR_E(TOP_E)

    const float denom = s1 + s2 + 1e-20f;
    const float n1 = s1 / denom;
    const float n2 = s2 / denom;

    *reinterpret_cast<float2*>(out + TOP_OFF + (size_t)tok * 2) =
        make_float2(n1, n2);
    *reinterpret_cast<float2*>(out + IDX_OFF + (size_t)tok * 2) =
        make_float2((float)i1, (float)i2);
    *reinterpret_cast<float4*>(out + SC_OFF + (size_t)tok * 8) =
        make_float4(sc_0, sc_1, sc_2, sc_3);
    *reinterpret_cast<float4*>(out + SC_OFF + (size_t)tok * 8 + 4) =
        make_float4(sc_4, sc_5, sc_6, sc_7);

    const float ent = -(n1 * __logf(n1) + n2 * __logf(n2));
    atomicAdd(&sEnt, ent);
    atomicAdd(&sHist[i1], 1);
    atomicAdd(&sHist[i2], 1);
  }

  __syncthreads();
  if (tid < NE) atomicAdd(out + HIST_OFF + tid, (float)sHist[tid]);
  if (tid == 0) atomicAdd(out + ENT_OFF, sEnt * (1.0f / (float)NT));
}

extern "C" void kernel_launch(void* const* d_in, const int* in_sizes, int n_in,
                              void* d_out, int out_size, void* d_ws, size_t ws_size,
                              hipStream_t stream) {
  (void)in_sizes; (void)n_in; (void)out_size; (void)d_ws; (void)ws_size;
  const float* x    = (const float*)d_in[0];
  const float* W    = (const float*)d_in[1];
  const float* bias = (const float*)d_in[2];
  float* out = (float*)d_out;

  // d_out is poisoned before timing: zero the atomic-accumulated tail first.
  init_tail<<<1, 64, 0, stream>>>(out);
  // 1024 blocks x 256 threads; 16 tokens/block; LDS 64.5 KiB -> 2 blocks/CU.
  router_kernel<<<1024, 256, 0, stream>>>(x, W, bias, out);
}

// Round 3
// 53.185 us; speedup vs baseline: 3.4694x; 1.0587x over previous
//
#include <hip/hip_runtime.h>
#include <math.h>

#define NT  16384
#define HID 2048
#define NE  8

constexpr int TOP_OFF  = 0;                 // top_scores  (NT,2)
constexpr int SC_OFF   = NT * 2;            // scores      (NT,8)
constexpr int IDX_OFF  = SC_OFF + NT * NE;  // indices     (NT,2)
constexpr int HIST_OFF = IDX_OFF + NT * 2;  // counts      (8)
constexpr int ENT_OFF  = HIST_OFF + NE;     // entropy     (1)

__global__ void init_tail(float* __restrict__ out) {
  const int i = threadIdx.x;
  if (i < NE + 1) out[HIST_OFF + i] = 0.0f;
}

// X-macro over experts: NAMED scalars only — no indexable per-thread arrays
// (round 1's arrays spilled ~210 MB of scratch to HBM; named scalars can't).
#define FOR_E(F) F(0) F(1) F(2) F(3) F(4) F(5) F(6) F(7)

// 512 threads = 8 waves/block; 64.5 KiB LDS -> 2 blocks/CU -> 16 waves/CU
// (4 waves/SIMD, 2x round-2's TLP). launch_bounds(512,4): 4 waves/EU min.
__global__ __launch_bounds__(512, 4)
void router_kernel(const float* __restrict__ x, const float* __restrict__ W,
                   const float* __restrict__ bias, float* __restrict__ out) {
  __shared__ float sW[NE * HID];   // 64 KiB
  __shared__ int   sHist[NE];
  __shared__ float sEnt;

  const int tid  = threadIdx.x;
  const int wave = tid >> 6;
  const int lane = tid & 63;

  // Stage W into LDS: 16384 floats = 4096 float4, 8 per thread (coalesced).
  {
    const float4* Wv  = reinterpret_cast<const float4*>(W);
    float4*       sWv = reinterpret_cast<float4*>(sW);
#pragma unroll
    for (int i = 0; i < 8; ++i) sWv[i * 512 + tid] = Wv[i * 512 + tid];
  }
  if (tid < NE) sHist[tid] = 0;
  if (tid == 0) sEnt = 0.0f;

#define DECL_BS(e) const float bs_##e = bias[e];
  FOR_E(DECL_BS)

  __syncthreads();

  // 4 tokens per wave, 32 per block, 512 blocks.
  const int t0 = blockIdx.x * 32 + wave * 4;
  const float* xb = x + (size_t)t0 * HID;

#define DECL_ACC(e) float a0_##e = 0.f, a1_##e = 0.f, a2_##e = 0.f, a3_##e = 0.f;
  FOR_E(DECL_ACC)

#pragma unroll
  for (int it = 0; it < 8; ++it) {
    const int off = it * 256 + lane * 4;  // element offset within a row
    const float4 x0 = *reinterpret_cast<const float4*>(xb + off);
    const float4 x1 = *reinterpret_cast<const float4*>(xb + HID + off);
    const float4 x2 = *reinterpret_cast<const float4*>(xb + 2 * HID + off);
    const float4 x3 = *reinterpret_cast<const float4*>(xb + 3 * HID + off);
#define STEP_E(e)                                                          \
    {                                                                      \
      const float4 wv = *reinterpret_cast<const float4*>(sW + e * HID + off); \
      a0_##e += x0.x * wv.x + x0.y * wv.y + x0.z * wv.z + x0.w * wv.w;     \
      a1_##e += x1.x * wv.x + x1.y * wv.y + x1.z * wv.z + x1.w * wv.w;     \
      a2_##e += x2.x * wv.x + x2.y * wv.y + x2.z * wv.z + x2.w * wv.w;     \
      a3_##e += x3.x * wv.x + x3.y * wv.y + x3.z * wv.z + x3.w * wv.w;     \
    }
    FOR_E(STEP_E)
  }

  // Butterfly reduce each named accumulator across all 64 lanes.
#define RED(v)                                                             \
  { v += __shfl_xor(v, 32, 64); v += __shfl_xor(v, 16, 64);                \
    v += __shfl_xor(v,  8, 64); v += __shfl_xor(v,  4, 64);                \
    v += __shfl_xor(v,  2, 64); v += __shfl_xor(v,  1, 64); }
#define RED_E(e) RED(a0_##e) RED(a1_##e) RED(a2_##e) RED(a3_##e)
  FOR_E(RED_E)

  // Lane l (<4) takes token t0+l's logits via cndmask chains (no arrays).
#define SEL_E(e)                                                           \
  float le_##e = a0_##e;                                                   \
  le_##e = (lane == 1) ? a1_##e : le_##e;                                  \
  le_##e = (lane == 2) ? a2_##e : le_##e;                                  \
  le_##e = (lane == 3) ? a3_##e : le_##e;
  FOR_E(SEL_E)

  if (lane < 4) {
    const int tok = t0 + lane;
#define SIG_E(e) const float sc_##e = 1.0f / (1.0f + __expf(-le_##e));
    FOR_E(SIG_E)

    // top-2 on biased scores; strict > keeps lowest index on ties (jax top_k)
    float m1 = -1e30f, m2 = -1e30f, s1 = 0.0f, s2 = 0.0f;
    int i1 = 0, i2 = 0;
#define TOP_E(e)                                                           \
    {                                                                      \
      const float be = sc_##e + bs_##e;                                    \
      const bool g1 = be > m1;                                             \
      const bool g2 = be > m2;                                             \
      i2 = g1 ? i1 : (g2 ? e     : i2);                                    \
      m2 = g1 ? m1 : (g2 ? be    : m2);                                    \
      s2 = g1 ? s1 : (g2 ? sc_##e : s2);                                   \
      i1 = g1 ? e     : i1;                                                \
      m1 = g1 ? be    : m1;                                                \
      s1 = g1 ? sc_##e : s1;                                               \
    }
    FOR_E(TOP_E)

    const float denom = s1 + s2 + 1e-20f;
    const float n1 = s1 / denom;
    const float n2 = s2 / denom;

    *reinterpret_cast<float2*>(out + TOP_OFF + (size_t)tok * 2) =
        make_float2(n1, n2);
    *reinterpret_cast<float2*>(out + IDX_OFF + (size_t)tok * 2) =
        make_float2((float)i1, (float)i2);
    *reinterpret_cast<float4*>(out + SC_OFF + (size_t)tok * 8) =
        make_float4(sc_0, sc_1, sc_2, sc_3);
    *reinterpret_cast<float4*>(out + SC_OFF + (size_t)tok * 8 + 4) =
        make_float4(sc_4, sc_5, sc_6, sc_7);

    const float ent = -(n1 * __logf(n1) + n2 * __logf(n2));
    atomicAdd(&sEnt, ent);
    atomicAdd(&sHist[i1], 1);
    atomicAdd(&sHist[i2], 1);
  }

  __syncthreads();
  if (tid < NE) atomicAdd(out + HIST_OFF + tid, (float)sHist[tid]);
  if (tid == 0) atomicAdd(out + ENT_OFF, sEnt * (1.0f / (float)NT));
}

extern "C" void kernel_launch(void* const* d_in, const int* in_sizes, int n_in,
                              void* d_out, int out_size, void* d_ws, size_t ws_size,
                              hipStream_t stream) {
  (void)in_sizes; (void)n_in; (void)out_size; (void)d_ws; (void)ws_size;
  const float* x    = (const float*)d_in[0];
  const float* W    = (const float*)d_in[1];
  const float* bias = (const float*)d_in[2];
  float* out = (float*)d_out;

  // d_out is poisoned before timing: zero the atomic-accumulated tail first.
  init_tail<<<1, 64, 0, stream>>>(out);
  // 512 blocks x 512 threads; 32 tokens/block.
  router_kernel<<<512, 512, 0, stream>>>(x, W, bias, out);
}

// Round 4
// 36.380 us; speedup vs baseline: 5.0720x; 1.4619x over previous
//
#include <hip/hip_runtime.h>
#include <math.h>

#define NT  16384
#define HID 2048
#define NE  8
#define NBLK 512   // router blocks

constexpr int TOP_OFF  = 0;                 // top_scores  (NT,2)
constexpr int SC_OFF   = NT * 2;            // scores      (NT,8)
constexpr int IDX_OFF  = SC_OFF + NT * NE;  // indices     (NT,2)
constexpr int HIST_OFF = IDX_OFF + NT * 2;  // counts      (8)
constexpr int ENT_OFF  = HIST_OFF + NE;     // entropy     (1)

// ws layout: float ws[NBLK][12] — [0..7]=hist, [8]=ent, [9..11]=pad
constexpr int WS_ROW = 12;

__global__ void init_tail(float* __restrict__ out) {
  const int i = threadIdx.x;
  if (i < NE + 1) out[HIST_OFF + i] = 0.0f;
}

// X-macro over experts: NAMED scalars only — no indexable per-thread arrays
// (round 1's arrays spilled ~210 MB of scratch to HBM).
#define FOR_E(F) F(0) F(1) F(2) F(3) F(4) F(5) F(6) F(7)

// 512 threads = 8 waves/block; 64.5 KiB LDS -> 2 blocks/CU -> 16 waves/CU.
// USE_WS=true: per-block partials to d_ws (no global atomics — round 3 showed
// the 4608 same-address cross-XCD atomics were the serialized tail).
template <bool USE_WS>
__global__ __launch_bounds__(512, 4)
void router_kernel(const float* __restrict__ x, const float* __restrict__ W,
                   const float* __restrict__ bias, float* __restrict__ out,
                   float* __restrict__ ws) {
  __shared__ float sW[NE * HID];   // 64 KiB
  __shared__ int   sHist[NE];
  __shared__ float sEnt;

  const int tid  = threadIdx.x;
  const int wave = tid >> 6;
  const int lane = tid & 63;

  // Stage W into LDS: 16384 floats = 4096 float4, 8 per thread (coalesced).
  {
    const float4* Wv  = reinterpret_cast<const float4*>(W);
    float4*       sWv = reinterpret_cast<float4*>(sW);
#pragma unroll
    for (int i = 0; i < 8; ++i) sWv[i * 512 + tid] = Wv[i * 512 + tid];
  }
  if (tid < NE) sHist[tid] = 0;
  if (tid == 0) sEnt = 0.0f;

#define DECL_BS(e) const float bs_##e = bias[e];
  FOR_E(DECL_BS)

  __syncthreads();

  // 4 tokens per wave, 32 per block, 512 blocks.
  const int t0 = blockIdx.x * 32 + wave * 4;
  const float* xb = x + (size_t)t0 * HID;
  // Column-phase rotation: concurrent waves/blocks start at different 1 KB
  // columns so the instantaneous HBM pattern isn't one 8 KB-strided column.
  const int phase = (wave + (int)blockIdx.x) & 7;

#define DECL_ACC(e) float a0_##e = 0.f, a1_##e = 0.f, a2_##e = 0.f, a3_##e = 0.f;
  FOR_E(DECL_ACC)

#pragma unroll
  for (int it = 0; it < 8; ++it) {
    const int itr = (it + phase) & 7;
    const int off = itr * 256 + lane * 4;  // element offset within a row
    const float4 x0 = *reinterpret_cast<const float4*>(xb + off);
    const float4 x1 = *reinterpret_cast<const float4*>(xb + HID + off);
    const float4 x2 = *reinterpret_cast<const float4*>(xb + 2 * HID + off);
    const float4 x3 = *reinterpret_cast<const float4*>(xb + 3 * HID + off);
#define STEP_E(e)                                                          \
    {                                                                      \
      const float4 wv = *reinterpret_cast<const float4*>(sW + e * HID + off); \
      a0_##e += x0.x * wv.x + x0.y * wv.y + x0.z * wv.z + x0.w * wv.w;     \
      a1_##e += x1.x * wv.x + x1.y * wv.y + x1.z * wv.z + x1.w * wv.w;     \
      a2_##e += x2.x * wv.x + x2.y * wv.y + x2.z * wv.z + x2.w * wv.w;     \
      a3_##e += x3.x * wv.x + x3.y * wv.y + x3.z * wv.z + x3.w * wv.w;     \
    }
    FOR_E(STEP_E)
  }

  // Butterfly reduce each named accumulator across all 64 lanes.
#define RED(v)                                                             \
  { v += __shfl_xor(v, 32, 64); v += __shfl_xor(v, 16, 64);                \
    v += __shfl_xor(v,  8, 64); v += __shfl_xor(v,  4, 64);                \
    v += __shfl_xor(v,  2, 64); v += __shfl_xor(v,  1, 64); }
#define RED_E(e) RED(a0_##e) RED(a1_##e) RED(a2_##e) RED(a3_##e)
  FOR_E(RED_E)

  // Lane l (<4) takes token t0+l's logits via cndmask chains (no arrays).
#define SEL_E(e)                                                           \
  float le_##e = a0_##e;                                                   \
  le_##e = (lane == 1) ? a1_##e : le_##e;                                  \
  le_##e = (lane == 2) ? a2_##e : le_##e;                                  \
  le_##e = (lane == 3) ? a3_##e : le_##e;
  FOR_E(SEL_E)

  if (lane < 4) {
    const int tok = t0 + lane;
#define SIG_E(e) const float sc_##e = 1.0f / (1.0f + __expf(-le_##e));
    FOR_E(SIG_E)

    // top-2 on biased scores; strict > keeps lowest index on ties (jax top_k)
    float m1 = -1e30f, m2 = -1e30f, s1 = 0.0f, s2 = 0.0f;
    int i1 = 0, i2 = 0;
#define TOP_E(e)                                                           \
    {                                                                      \
      const float be = sc_##e + bs_##e;                                    \
      const bool g1 = be > m1;                                             \
      const bool g2 = be > m2;                                             \
      i2 = g1 ? i1 : (g2 ? e     : i2);                                    \
      m2 = g1 ? m1 : (g2 ? be    : m2);                                    \
      s2 = g1 ? s1 : (g2 ? sc_##e : s2);                                   \
      i1 = g1 ? e     : i1;                                                \
      m1 = g1 ? be    : m1;                                                \
      s1 = g1 ? sc_##e : s1;                                               \
    }
    FOR_E(TOP_E)

    const float denom = s1 + s2 + 1e-20f;
    const float n1 = s1 / denom;
    const float n2 = s2 / denom;

    *reinterpret_cast<float2*>(out + TOP_OFF + (size_t)tok * 2) =
        make_float2(n1, n2);
    *reinterpret_cast<float2*>(out + IDX_OFF + (size_t)tok * 2) =
        make_float2((float)i1, (float)i2);
    *reinterpret_cast<float4*>(out + SC_OFF + (size_t)tok * 8) =
        make_float4(sc_0, sc_1, sc_2, sc_3);
    *reinterpret_cast<float4*>(out + SC_OFF + (size_t)tok * 8 + 4) =
        make_float4(sc_4, sc_5, sc_6, sc_7);

    const float ent = -(n1 * __logf(n1) + n2 * __logf(n2));
    atomicAdd(&sEnt, ent);
    atomicAdd(&sHist[i1], 1);
    atomicAdd(&sHist[i2], 1);
  }

  __syncthreads();
  if (USE_WS) {
    // Plain coalesced partial stores — zero global atomics.
    if (tid < NE) ws[(size_t)blockIdx.x * WS_ROW + tid] = (float)sHist[tid];
    if (tid == NE) ws[(size_t)blockIdx.x * WS_ROW + NE] = sEnt;
  } else {
    if (tid < NE) atomicAdd(out + HIST_OFF + tid, (float)sHist[tid]);
    if (tid == 0) atomicAdd(out + ENT_OFF, sEnt * (1.0f / (float)NT));
  }
}

// One wave reduces 512 partial rows; writes counts + entropy directly
// (overwrites poison — no pre-zeroing needed).
__global__ void finalize(const float* __restrict__ ws, float* __restrict__ out) {
  const int lane = threadIdx.x & 63;
  float h0 = 0.f, h1 = 0.f, h2 = 0.f, h3 = 0.f;
  float h4 = 0.f, h5 = 0.f, h6 = 0.f, h7 = 0.f, ent = 0.f;
#pragma unroll
  for (int r = 0; r < NBLK / 64; ++r) {   // 8 rows per lane, static offsets
    const float* p = ws + (size_t)(r * 64 + lane) * WS_ROW;
    h0 += p[0]; h1 += p[1]; h2 += p[2]; h3 += p[3];
    h4 += p[4]; h5 += p[5]; h6 += p[6]; h7 += p[7];
    ent += p[8];
  }
#define REDF(v)                                                            \
  { v += __shfl_xor(v, 32, 64); v += __shfl_xor(v, 16, 64);                \
    v += __shfl_xor(v,  8, 64); v += __shfl_xor(v,  4, 64);                \
    v += __shfl_xor(v,  2, 64); v += __shfl_xor(v,  1, 64); }
  REDF(h0) REDF(h1) REDF(h2) REDF(h3) REDF(h4) REDF(h5) REDF(h6) REDF(h7)
  REDF(ent)
  if (lane == 0) {
    out[HIST_OFF + 0] = h0; out[HIST_OFF + 1] = h1;
    out[HIST_OFF + 2] = h2; out[HIST_OFF + 3] = h3;
    out[HIST_OFF + 4] = h4; out[HIST_OFF + 5] = h5;
    out[HIST_OFF + 6] = h6; out[HIST_OFF + 7] = h7;
    out[ENT_OFF] = ent * (1.0f / (float)NT);
  }
}

extern "C" void kernel_launch(void* const* d_in, const int* in_sizes, int n_in,
                              void* d_out, int out_size, void* d_ws, size_t ws_size,
                              hipStream_t stream) {
  (void)in_sizes; (void)n_in; (void)out_size;
  const float* x    = (const float*)d_in[0];
  const float* W    = (const float*)d_in[1];
  const float* bias = (const float*)d_in[2];
  float* out = (float*)d_out;

  const bool use_ws = (d_ws != nullptr) &&
                      (ws_size >= (size_t)NBLK * WS_ROW * sizeof(float));
  if (use_ws) {
    router_kernel<true><<<NBLK, 512, 0, stream>>>(x, W, bias, out, (float*)d_ws);
    finalize<<<1, 64, 0, stream>>>((const float*)d_ws, out);
  } else {
    init_tail<<<1, 64, 0, stream>>>(out);
    router_kernel<false><<<NBLK, 512, 0, stream>>>(x, W, bias, out, (float*)d_ws);
  }
}